// Round 13
// baseline (308.198 us; speedup 1.0000x reference)
//
#include <hip/hip_runtime.h>
#include <hip/hip_bf16.h>
#include <stdint.h>

#define CIN   448
#define DP    100
#define NPIX  4096
#define LNUM  4096
#define KQ    5050      // packed upper-triangle columns
#define KLIN  5150      // + 100 linear columns
#define KTOT  5184      // padded to 81*64
#define KSTEPS (KTOT / 64)
#define OUTHW 256
#define ICS   104       // padded LDS stride for buildB

typedef _Float16 f16_t;
typedef _Float16 f16x8 __attribute__((ext_vector_type(8)));
typedef float    f32x4 __attribute__((ext_vector_type(4)));
typedef unsigned short u16x8 __attribute__((ext_vector_type(8)));

static __device__ __forceinline__ int tri_off(int d) { return (d * (201 - d)) >> 1; }

static __device__ __forceinline__ void unpack_tri(int k, int& d, int& e) {
    int dd = (int)((201.0f - sqrtf(40401.0f - 8.0f * (float)k)) * 0.5f);
    if (dd < 0) dd = 0;
    if (dd > 99) dd = 99;
    while (tri_off(dd + 1) <= k) ++dd;
    while (tri_off(dd) > k) --dd;
    d = dd;
    e = dd + (k - tri_off(dd));
}

static __device__ __forceinline__ unsigned f2u(float x) {
    unsigned b = __float_as_uint(x);
    return (b & 0x80000000u) ? ~b : (b | 0x80000000u);
}
static __device__ __forceinline__ float u2f(unsigned u) {
    unsigned b = (u & 0x80000000u) ? (u & 0x7FFFFFFFu) : ~u;
    return __uint_as_float(b);
}

static __device__ __forceinline__ void gload_lds16(const f16_t* g, f16_t* l) {
    __builtin_amdgcn_global_load_lds((const __attribute__((address_space(1))) unsigned*)g,
                                     (__attribute__((address_space(3))) unsigned*)l,
                                     16, 0, 0);
}

// ---------------- kernel 0: tri-unpack LUT + init per-row min ----------------
__global__ void k_lut(unsigned short* __restrict__ lut, unsigned* __restrict__ mind) {
    int k = blockIdx.x * 256 + threadIdx.x;
    if (k < KTOT) {
        int d = 0, e = 0;
        if (k < KQ) unpack_tri(k, d, e);
        lut[k] = (unsigned short)(d | (e << 8));
    }
    if (k < NPIX) mind[k] = 0xFFFFFFFFu;
}

// ---------------- kernel 1: projection f[n,d] = feat[:,n] . w[d,:] + b[d] ----------------
__global__ void k_proj(const float* __restrict__ feat, const float* __restrict__ w,
                       const float* __restrict__ b, float* __restrict__ f) {
    int gid = blockIdx.x * 256 + threadIdx.x;   // 409600 = 4096*100
    int n = gid & 4095;
    int d = gid >> 12;
    float acc = b[d];
    const float* wd = w + d * CIN;
    #pragma unroll 4
    for (int c = 0; c < CIN; ++c) acc += feat[c * 4096 + n] * wd[c];
    f[n * DP + d] = acc;
}

// ---------------- kernel 2: build A, tiled+swizzled ----------------
__global__ __launch_bounds__(256) void k_buildA(const float* __restrict__ f, const unsigned short* __restrict__ lut,
                                                f16_t* __restrict__ A) {
    __shared__ float fr[DP];
    int n = blockIdx.x;
    int t = threadIdx.x;
    if (t < DP) fr[t] = f[n * DP + t];
    __syncthreads();
    int r  = n & 127;
    int rsw = (r & 7) << 3;
    f16_t* tileBase = A + (size_t)(n >> 7) * KSTEPS * 8192;
    for (int g = t; g < KTOT / 8; g += 256) {
        int k0 = g * 8;
        u16x8 lu = *(const u16x8*)&lut[k0];
        f16x8 v;
        #pragma unroll
        for (int j = 0; j < 8; ++j) {
            int k = k0 + j;
            float x;
            if (k < KQ) {
                int d = lu[j] & 255, e = lu[j] >> 8;
                x = fr[d] * fr[e];
            } else if (k < KLIN) {
                x = fr[k - KQ];
            } else {
                x = 0.0f;
            }
            v[j] = (f16_t)x;
        }
        int kt = k0 >> 6, kin = k0 & 63;
        *(f16x8*)&tileBase[kt * 8192 + r * 64 + ((kin & 56) ^ rsw)] = v;
    }
}

// ---------------- kernel 3: build B (ic stride 104, float4 icm) + const[l] ----------------
__global__ __launch_bounds__(256) void k_buildB(const float* __restrict__ icov, const float* __restrict__ mean,
                                                const unsigned short* __restrict__ lut,
                                                f16_t* __restrict__ Bm, float* __restrict__ constl) {
    __shared__ float ic[DP * ICS];
    __shared__ float ml[ICS];
    __shared__ float wv[DP];
    __shared__ float part[DP];
    int l = blockIdx.x;
    int t = threadIdx.x;
    const float4* src4 = (const float4*)(icov + (size_t)l * DP * DP);
    for (int i4 = t; i4 < DP * DP / 4; i4 += 256) {
        float4 v = src4[i4];
        int flat = i4 * 4;
        int row = flat / 100;
        int col = flat - row * 100;
        float* dst = &ic[row * ICS + col];
        dst[0] = v.x; dst[1] = v.y; dst[2] = v.z; dst[3] = v.w;
    }
    if (t < DP) {
        ic[t * ICS + 100] = 0.f; ic[t * ICS + 101] = 0.f;
        ic[t * ICS + 102] = 0.f; ic[t * ICS + 103] = 0.f;
        ml[t] = mean[t * LNUM + l];
    }
    if (t >= DP && t < ICS) ml[t] = 0.f;
    __syncthreads();
    if (t < DP) {
        float icm = 0.f;
        const f32x4* icr = (const f32x4*)&ic[t * ICS];
        const f32x4* mlr = (const f32x4*)&ml[0];
        #pragma unroll
        for (int e4 = 0; e4 < ICS / 4; ++e4) {
            f32x4 a = icr[e4], m = mlr[e4];
            icm += a.x * m.x + a.y * m.y + a.z * m.z + a.w * m.w;
        }
        float ictm = 0.f;
        for (int e = 0; e < DP; ++e) ictm += ic[e * ICS + t] * ml[e];
        wv[t]   = icm + ictm;
        part[t] = ml[t] * icm;
    }
    __syncthreads();
    if (t == 0) {
        float c = 0.f;
        for (int d = 0; d < DP; ++d) c += part[d];
        constl[l] = c;
    }
    int r  = l & 127;
    int rsw = (r & 7) << 3;
    f16_t* tileBase = Bm + (size_t)(l >> 7) * KSTEPS * 8192;
    for (int g = t; g < KTOT / 8; g += 256) {
        int k0 = g * 8;
        u16x8 lu = *(const u16x8*)&lut[k0];
        f16x8 v;
        #pragma unroll
        for (int j = 0; j < 8; ++j) {
            int k = k0 + j;
            float x;
            if (k < KQ) {
                int d = lu[j] & 255, e = lu[j] >> 8;
                float s = ic[d * ICS + e] + ic[e * ICS + d];
                x = (d == e) ? 0.5f * s : s;
            } else if (k < KLIN) {
                x = -wv[k - KQ];
            } else {
                x = 0.0f;
            }
            v[j] = (f16_t)x;
        }
        int kt = k0 >> 6, kin = k0 & 63;
        *(f16x8*)&tileBase[kt * 8192 + r * 64 + ((kin & 56) ^ rsw)] = v;
    }
}

// ---------------- kernel 4: 256^2 window-pipelined 4-phase MFMA GEMM ----------------
// 8 waves (2M x 4N), per-wave 128x64 C. 2-side LDS (128KB), grid 256 = 1 block/CU.
// Window T: burst-stage tile T+1 -> side ^1 (its previous reads completed last window);
// 4 phases {A-quadrant ds_read (+B at q=0) | barrier | setprio+16 MFMA | barrier};
// terminal vmcnt(0) waits loads issued a full window (~2400cy) earlier -> ~0 stall.
// Race-free by construction: stages only touch the non-consumed side, issued after the
// barrier that ends that side's reads; reads only touch the side certified last window.
__global__ __launch_bounds__(512, 1) void k_gemm(const f16_t* __restrict__ A, const f16_t* __restrict__ Bm,
                                                 const float* __restrict__ constl, unsigned* __restrict__ mind) {
    __shared__ __align__(16) f16_t sA[2][16384];   // [side][half*8192 + row*64 + swz-k]
    __shared__ __align__(16) f16_t sB[2][16384];

    int bid = blockIdx.x;                        // 256 blocks (16 x 16)
    int pid = ((bid & 7) << 5) | (bid >> 3);     // XCD swizzle, bijective
    int bm = pid & 15;
    int bn = pid >> 4;

    int t = threadIdx.x;
    int lane = t & 63;
    int w = t >> 6;                              // 0..7
    int wr = w >> 2;                             // 0..1 (M half)
    int wc = w & 3;                              // 0..3 (N quarter)

    f32x4 acc[8][4];
    #pragma unroll
    for (int i = 0; i < 8; ++i)
        #pragma unroll
        for (int j = 0; j < 4; ++j) acc[i][j] = (f32x4){0.f, 0.f, 0.f, 0.f};

    const f16_t* g0 = A  + (size_t)(2 * bm)     * KSTEPS * 8192;
    const f16_t* g1 = A  + (size_t)(2 * bm + 1) * KSTEPS * 8192;
    const f16_t* g2 = Bm + (size_t)(2 * bn)     * KSTEPS * 8192;
    const f16_t* g3 = Bm + (size_t)(2 * bn + 1) * KSTEPS * 8192;

    int soff = w * 512 + lane * 8;               // per-thread src offset in a half-tile
    int dofs = w * 512;                          // wave-uniform LDS dest offset

    int l15 = lane & 15;
    int xorv = (lane & 7) << 3;
    int klobase = (lane >> 4) * 8;

    // prologue: stage tile 0 into side 0
    {
        gload_lds16(g0 + soff, &sA[0][dofs]);            gload_lds16(g0 + 4096 + soff, &sA[0][4096 + dofs]);
        gload_lds16(g1 + soff, &sA[0][8192 + dofs]);     gload_lds16(g1 + 4096 + soff, &sA[0][12288 + dofs]);
        gload_lds16(g2 + soff, &sB[0][dofs]);            gload_lds16(g2 + 4096 + soff, &sB[0][4096 + dofs]);
        gload_lds16(g3 + soff, &sB[0][8192 + dofs]);     gload_lds16(g3 + 4096 + soff, &sB[0][12288 + dofs]);
    }
    asm volatile("s_waitcnt vmcnt(0)" ::: "memory");
    __builtin_amdgcn_s_barrier();

    for (int T = 0; T < KSTEPS; ++T) {
        int s = T & 1;
        if (T + 1 < KSTEPS) {   // burst-stage tile T+1 into side s^1
            size_t go = (size_t)(T + 1) * 8192;
            int d = s ^ 1;
            gload_lds16(g0 + go + soff, &sA[d][dofs]);          gload_lds16(g0 + go + 4096 + soff, &sA[d][4096 + dofs]);
            gload_lds16(g1 + go + soff, &sA[d][8192 + dofs]);   gload_lds16(g1 + go + 4096 + soff, &sA[d][12288 + dofs]);
            gload_lds16(g2 + go + soff, &sB[d][dofs]);          gload_lds16(g2 + go + 4096 + soff, &sB[d][4096 + dofs]);
            gload_lds16(g3 + go + soff, &sB[d][8192 + dofs]);   gload_lds16(g3 + go + 4096 + soff, &sB[d][12288 + dofs]);
        }
        f16x8 bfr[4][2];
        #pragma unroll
        for (int q = 0; q < 4; ++q) {
            if (q == 0) {   // B-frags for the whole window, held in regs
                #pragma unroll
                for (int ni = 0; ni < 4; ++ni)
                    #pragma unroll
                    for (int kk = 0; kk < 2; ++kk) {
                        int rr = (wc & 1) * 64 + ni * 16 + l15;
                        bfr[ni][kk] = *(const f16x8*)&sB[s][(wc >> 1) * 8192 + rr * 64 + ((kk * 32 + klobase) ^ xorv)];
                    }
            }
            f16x8 afr[2][2];
            #pragma unroll
            for (int miL = 0; miL < 2; ++miL)
                #pragma unroll
                for (int kk = 0; kk < 2; ++kk) {
                    int rr = (2 * q + miL) * 16 + l15;
                    afr[miL][kk] = *(const f16x8*)&sA[s][wr * 8192 + rr * 64 + ((kk * 32 + klobase) ^ xorv)];
                }
            __builtin_amdgcn_sched_barrier(0);
            __builtin_amdgcn_s_barrier();            // phase barrier A (role split)
            __builtin_amdgcn_s_setprio(1);
            #pragma unroll
            for (int kk = 0; kk < 2; ++kk)
                #pragma unroll
                for (int miL = 0; miL < 2; ++miL)
                    #pragma unroll
                    for (int ni = 0; ni < 4; ++ni)
                        acc[2 * q + miL][ni] =
                            __builtin_amdgcn_mfma_f32_16x16x32_f16(afr[miL][kk], bfr[ni][kk], acc[2 * q + miL][ni], 0, 0, 0);
            __builtin_amdgcn_s_setprio(0);
            __builtin_amdgcn_sched_barrier(0);
            __builtin_amdgcn_s_barrier();            // phase barrier B
        }
        asm volatile("s_waitcnt vmcnt(0)" ::: "memory");   // tile T+1 landed (issued a window ago)
        __builtin_amdgcn_s_barrier();                      // side s^1 certified for all waves
    }

    // epilogue: dist = acc + const[col]; min over block cols per row; atomicMin (r10-proven)
    int colbase = bn * 256 + wc * 64 + l15;
    float cl[4];
    #pragma unroll
    for (int ni = 0; ni < 4; ++ni) cl[ni] = constl[colbase + ni * 16];
    #pragma unroll
    for (int mi8 = 0; mi8 < 8; ++mi8) {
        #pragma unroll
        for (int j = 0; j < 4; ++j) {
            float v = 1e30f;
            #pragma unroll
            for (int ni = 0; ni < 4; ++ni) v = fminf(v, acc[mi8][ni][j] + cl[ni]);
            #pragma unroll
            for (int s = 1; s < 16; s <<= 1) v = fminf(v, __shfl_xor(v, s, 64));
            if (l15 == 0) {
                int row = bm * 256 + wr * 128 + mi8 * 16 + (lane >> 4) * 4 + j;
                atomicMin(&mind[row], f2u(v));
            }
        }
    }
}

// ---------------- kernel 5: normalize + bilinear upsample (min/max fused per block) ----------------
__global__ __launch_bounds__(256) void k_upsample(const unsigned* __restrict__ mind, float* __restrict__ out) {
    __shared__ float smin[256], smax[256];
    int t = threadIdx.x;
    float vmin = 1e30f, vmax = -1e30f;
    for (int i = t; i < NPIX; i += 256) {
        float v = u2f(mind[i]);
        vmin = fminf(vmin, v);
        vmax = fmaxf(vmax, v);
    }
    smin[t] = vmin; smax[t] = vmax;
    __syncthreads();
    for (int s = 128; s > 0; s >>= 1) {
        if (t < s) {
            smin[t] = fminf(smin[t], smin[t + s]);
            smax[t] = fmaxf(smax[t], smax[t + s]);
        }
        __syncthreads();
    }
    float gmin = smin[0];
    float scale = 1.0f / (smax[0] - smin[0] + 1e-8f);

    int gid = blockIdx.x * 256 + t;             // 65536
    int i = gid >> 8, j = gid & 255;
    float x = fminf(fmaxf(j * 0.25f - 0.375f, 0.0f), 63.0f);
    float y = fminf(fmaxf(i * 0.25f - 0.375f, 0.0f), 63.0f);
    int x0 = (int)x, y0 = (int)y;
    int x1 = min(x0 + 1, 63), y1 = min(y0 + 1, 63);
    float fx = x - x0, fy = y - y0;
    float v00 = u2f(mind[y0 * 64 + x0]), v01 = u2f(mind[y0 * 64 + x1]);
    float v10 = u2f(mind[y1 * 64 + x0]), v11 = u2f(mind[y1 * 64 + x1]);
    float v = v00 * (1.f - fy) * (1.f - fx) + v01 * (1.f - fy) * fx
            + v10 * fy * (1.f - fx) + v11 * fy * fx;
    out[gid] = (v - gmin) * scale;
}

// ---------------- diagnostic: ws too small -> uniform 0.25 output ----------------
__global__ void k_diag(float* __restrict__ out) {
    int gid = blockIdx.x * 256 + threadIdx.x;
    out[gid] = 0.25f;
}

extern "C" void kernel_launch(void* const* d_in, const int* in_sizes, int n_in,
                              void* d_out, int out_size, void* d_ws, size_t ws_size,
                              hipStream_t stream) {
    const float* feat = (const float*)d_in[0];
    const float* pw   = (const float*)d_in[1];
    const float* pb   = (const float*)d_in[2];
    const float* mean = (const float*)d_in[3];
    const float* icov = (const float*)d_in[4];

    size_t need = 0;
    auto count = [&need](size_t bytes) { need = ((need + 255) & ~(size_t)255) + bytes; };
    count((size_t)NPIX * DP * 4);
    count((size_t)NPIX * KTOT * 2);
    count((size_t)LNUM * KTOT * 2);
    count((size_t)LNUM * 4);
    count((size_t)NPIX * 4);
    count((size_t)KTOT * 2);
    if (ws_size < need) {
        k_diag<<<256, 256, 0, stream>>>((float*)d_out);
        return;
    }

    char* ws = (char*)d_ws;
    size_t off = 0;
    auto alloc = [&](size_t bytes) -> void* {
        off = (off + 255) & ~(size_t)255;
        void* p = ws + off;
        off += bytes;
        return p;
    };
    float*          f      = (float*)alloc((size_t)NPIX * DP * 4);
    f16_t*          Amat   = (f16_t*)alloc((size_t)NPIX * KTOT * 2);
    f16_t*          Bmat   = (f16_t*)alloc((size_t)LNUM * KTOT * 2);
    float*          constl = (float*)alloc((size_t)LNUM * 4);
    unsigned*       mind   = (unsigned*)alloc((size_t)NPIX * 4);
    unsigned short* lut    = (unsigned short*)alloc((size_t)KTOT * 2);

    k_lut     <<<(KTOT + 255) / 256, 256, 0, stream>>>(lut, mind);
    k_proj    <<<1600, 256, 0, stream>>>(feat, pw, pb, f);
    k_buildA  <<<NPIX, 256, 0, stream>>>(f, lut, Amat);
    k_buildB  <<<LNUM, 256, 0, stream>>>(icov, mean, lut, Bmat, constl);
    k_gemm    <<<256, 512, 0, stream>>>(Amat, Bmat, constl, mind);
    k_upsample<<<256, 256, 0, stream>>>(mind, (float*)d_out);
}